// Round 3
// baseline (350.167 us; speedup 1.0000x reference)
//
#include <hip/hip_runtime.h>

#define BN    32768   // B*N
#define KNB   12
#define DIM   128

typedef __attribute__((ext_vector_type(8))) short bf16x8;
typedef __attribute__((ext_vector_type(4))) float f32x4;

__device__ inline unsigned short f2b(float x) {
    union { float f; unsigned u; } v; v.f = x;
    unsigned r = v.u + 0x7fffu + ((v.u >> 16) & 1u);   // RNE
    return (unsigned short)(r >> 16);
}
__device__ inline float b2f(unsigned short s) {
    union { unsigned u; float f; } v; v.u = ((unsigned)s) << 16; return v.f;
}
__device__ inline unsigned pack2(float a, float b) {
    return (unsigned)f2b(a) | ((unsigned)f2b(b) << 16);
}

// ---------------------------------------------------------------------------
// Prep: w1 (128x128 part) and w3 (256x128) -> bf16 MFMA B-fragment order.
// frag fi, lane, j -> B[k = ks*32 + (lane>>4)*8 + j][n = nt*16 + (lane&15)]
// w1f: fi = nt*4 + ks (nt 0..7, ks 0..3);  w3f: fi = nt*8 + ks (nt 0..7, ks 0..7)
// ---------------------------------------------------------------------------
__global__ void prep_kernel(const float* __restrict__ w1, const float* __restrict__ w3,
                            unsigned short* __restrict__ w1f, unsigned short* __restrict__ w3f) {
    int idx = blockIdx.x * 256 + threadIdx.x;
    if (idx < 16384) {
        int j = idx & 7, lane = (idx >> 3) & 63, fi = idx >> 9;
        int nt = fi >> 2, ks = fi & 3;
        int k = ks * 32 + (lane >> 4) * 8 + j;
        int n = nt * 16 + (lane & 15);
        w1f[idx] = f2b(w1[k * DIM + n]);
    }
    if (idx < 32768) {
        int j = idx & 7, lane = (idx >> 3) & 63, fi = idx >> 9;
        int nt = fi >> 3, ks = fi & 7;
        int k = ks * 32 + (lane >> 4) * 8 + j;
        int n = nt * 16 + (lane & 15);
        w3f[idx] = f2b(w3[k * DIM + n]);
    }
}

// ---------------------------------------------------------------------------
// Fused kernel: block = 8 nodes.
//  1) stage neighbor -> bf16 nbrb + featb (feat = extra * nbr) in LDS
//  2) GEMM1 alpha[96,128] = featb @ w1 (B-frags streamed from global/L1),
//     epilogue: + nw * w1[128,:], leaky_relu, dot w2 -> logits[96]
//  3) softmax over K=12 -> wts
//  4) agg[8,128] from nbrb * wts; A2 = [self || agg] bf16 (reuses featb LDS)
//  5) GEMM2 out[8,128] = relu(A2 @ w3), w3 B-frags from global/L1
// ---------------------------------------------------------------------------
#define T1   8
#define M1   96
#define LDA1 136    // 128 + 8 pad shorts (17 x 16B -> odd b128 stride)
#define LDA2 264    // 256 + 8 pad shorts (33 x 16B -> odd b128 stride)

__global__ __launch_bounds__(256) void fused_kernel(
    const float* __restrict__ nbr_g,   // [BN,12,128]
    const float* __restrict__ nw_g,    // [BN,12]
    const float* __restrict__ ext_g,   // [BN,128]
    const float* __restrict__ selfv,   // [BN,128]
    const float* __restrict__ w1,      // [129,128] (row 128 used in epilogue)
    const float* __restrict__ w2,      // [128]
    const unsigned short* __restrict__ w1f,
    const unsigned short* __restrict__ w3f,
    float* __restrict__ out)           // [BN,128]
{
    __shared__ unsigned short featb[M1 * LDA1];   // 26112 B; reused as A2 (needs 8448 B)
    __shared__ unsigned short nbrb[M1 * LDA1];    // 26112 B
    __shared__ float logits[M1];
    __shared__ float wts[M1];

    const int tid  = threadIdx.x;
    const int lane = tid & 63;
    const int wv   = tid >> 6;
    const int bn0  = blockIdx.x * T1;

    // ---- 1) stage neighbor (3072 float4) -> bf16 nbr + bf16 feat ----
    const float4* nsrc  = (const float4*)(nbr_g + (size_t)bn0 * KNB * DIM);
    const float*  ebase = ext_g + (size_t)bn0 * DIM;
    #pragma unroll 6
    for (int i = 0; i < 12; ++i) {
        int f4  = tid + i * 256;          // 0..3071
        int row = f4 >> 5;                // 32 float4 per row
        int c4  = f4 & 31;
        int node = row / 12;
        float4 nv = nsrc[f4];
        float4 ev = *(const float4*)(ebase + node * DIM + c4 * 4);
        uint2 pn; pn.x = pack2(nv.x, nv.y);               pn.y = pack2(nv.z, nv.w);
        uint2 pf; pf.x = pack2(nv.x * ev.x, nv.y * ev.y); pf.y = pack2(nv.z * ev.z, nv.w * ev.w);
        *(uint2*)&nbrb [row * LDA1 + c4 * 4] = pn;
        *(uint2*)&featb[row * LDA1 + c4 * 4] = pf;
    }
    __syncthreads();

    const int m    = lane & 15;
    const int quad = lane >> 4;

    // per-lane epilogue constants (L1-resident)
    float w2v[8], w1l[8];
    #pragma unroll
    for (int nt = 0; nt < 8; ++nt) {
        w2v[nt] = w2[nt * 16 + m];
        w1l[nt] = w1[DIM * DIM + nt * 16 + m];
    }

    // ---- 2) GEMM1 + logits: 6 M-tiles over 4 waves; B-frags from global ----
    const bf16x8* w1fv = (const bf16x8*)w1f;
    for (int mt = wv; mt < 6; mt += 4) {
        const int rowbase = mt * 16 + quad * 4;
        float nwv[4];
        #pragma unroll
        for (int r = 0; r < 4; ++r) nwv[r] = nw_g[(size_t)bn0 * KNB + rowbase + r];

        bf16x8 af[4];
        #pragma unroll
        for (int ks = 0; ks < 4; ++ks)
            af[ks] = *(const bf16x8*)&featb[(mt * 16 + m) * LDA1 + ks * 32 + quad * 8];

        float lp[4] = {0.f, 0.f, 0.f, 0.f};
        #pragma unroll
        for (int nt = 0; nt < 8; ++nt) {
            f32x4 acc = {0.f, 0.f, 0.f, 0.f};
            #pragma unroll
            for (int ks = 0; ks < 4; ++ks)
                acc = __builtin_amdgcn_mfma_f32_16x16x32_bf16(af[ks], w1fv[(nt * 4 + ks) * 64 + lane], acc, 0, 0, 0);
            #pragma unroll
            for (int r = 0; r < 4; ++r) {
                float v = acc[r] + nwv[r] * w1l[nt];   // 129th feature
                v = v > 0.f ? v : 0.2f * v;            // leaky_relu(0.2)
                lp[r] += v * w2v[nt];
            }
        }
        #pragma unroll
        for (int r = 0; r < 4; ++r) {
            float v = lp[r];
            v += __shfl_xor(v, 1, 64); v += __shfl_xor(v, 2, 64);
            v += __shfl_xor(v, 4, 64); v += __shfl_xor(v, 8, 64);
            if (m == 0) logits[rowbase + r] = v;
        }
    }
    __syncthreads();   // logits ready; featb free -> reuse as A2

    unsigned short* A2 = featb;   // [16 x LDA2] rows 0..7 real

    // ---- 4a) stage self rows into A2 cols 0..127 (all threads) ----
    {
        const int r  = tid >> 5;          // 0..7
        const int c4 = tid & 31;
        float4 v = *(const float4*)(selfv + (size_t)(bn0 + r) * DIM + c4 * 4);
        uint2 p; p.x = pack2(v.x, v.y); p.y = pack2(v.z, v.w);
        *(uint2*)&A2[r * LDA2 + c4 * 4] = p;
    }
    // ---- 3) softmax over K=12 (8 threads) ----
    if (tid < T1) {
        float mx = logits[tid * KNB];
        #pragma unroll
        for (int k = 1; k < KNB; ++k) mx = fmaxf(mx, logits[tid * KNB + k]);
        float s = 0.f; float e[KNB];
        #pragma unroll
        for (int k = 0; k < KNB; ++k) { e[k] = __expf(logits[tid * KNB + k] - mx); s += e[k]; }
        float inv = 1.f / s;
        #pragma unroll
        for (int k = 0; k < KNB; ++k) wts[tid * KNB + k] = e[k] * inv;
    }
    __syncthreads();

    // ---- 4b) agg from nbrb -> A2 cols 128..255 ----
    {
        const int node = tid >> 5;
        const int dd   = (tid & 31) * 4;
        float a0 = 0.f, a1 = 0.f, a2 = 0.f, a3 = 0.f;
        #pragma unroll
        for (int k = 0; k < KNB; ++k) {
            float w = wts[node * KNB + k];
            uint2 pk = *(const uint2*)&nbrb[(node * KNB + k) * LDA1 + dd];
            a0 += w * b2f((unsigned short)(pk.x & 0xffff));
            a1 += w * b2f((unsigned short)(pk.x >> 16));
            a2 += w * b2f((unsigned short)(pk.y & 0xffff));
            a3 += w * b2f((unsigned short)(pk.y >> 16));
        }
        uint2 po; po.x = pack2(a0, a1); po.y = pack2(a2, a3);
        *(uint2*)&A2[node * LDA2 + 128 + dd] = po;
    }
    __syncthreads();

    // ---- 5) GEMM2: out[8,128] = relu(A2[8,256] @ w3); wave wv -> nt 2wv,2wv+1 ----
    {
        const bf16x8* w3fv = (const bf16x8*)w3f;
        bf16x8 af2[8];
        #pragma unroll
        for (int ks = 0; ks < 8; ++ks)
            af2[ks] = *(const bf16x8*)&A2[m * LDA2 + ks * 32 + quad * 8];

        #pragma unroll
        for (int t = 0; t < 2; ++t) {
            const int nt = wv * 2 + t;
            f32x4 acc = {0.f, 0.f, 0.f, 0.f};
            #pragma unroll
            for (int ks = 0; ks < 8; ++ks)
                acc = __builtin_amdgcn_mfma_f32_16x16x32_bf16(af2[ks], w3fv[(nt * 8 + ks) * 64 + lane], acc, 0, 0, 0);
            #pragma unroll
            for (int r = 0; r < 4; ++r) {
                const int rl = quad * 4 + r;
                if (rl < T1)
                    out[(size_t)(bn0 + rl) * DIM + nt * 16 + m] = fmaxf(acc[r], 0.f);
            }
        }
    }
}

// ===========================================================================
// Fallback fp32 path if ws can't hold the 96 KB weight fragments.
// ===========================================================================
__global__ __launch_bounds__(128) void attn_agg_fb(
    const float* __restrict__ neighbor, const float* __restrict__ nw,
    const float* __restrict__ extra, const float* __restrict__ w1,
    const float* __restrict__ w2, float* __restrict__ agg)
{
    __shared__ float nbr_lds[2][KNB * DIM];
    const int wave = threadIdx.x >> 6, lane = threadIdx.x & 63;
    const int bn = blockIdx.x * 2 + wave;
    const float* nbr_gp = neighbor + (size_t)bn * (KNB * DIM);
    const float* ext_gp = extra + (size_t)bn * DIM;
    {
        const float4* s = (const float4*)nbr_gp;
        float4* d4 = (float4*)nbr_lds[wave];
        #pragma unroll
        for (int j = 0; j < 6; ++j) d4[lane + j * 64] = s[lane + j * 64];
    }
    __syncthreads();
    const int d0 = lane, d1 = lane + 64;
    float acc0[KNB], acc1[KNB];
    #pragma unroll
    for (int k = 0; k < KNB; ++k) { acc0[k] = 0.f; acc1[k] = 0.f; }
    const float* nbr_s = nbr_lds[wave];
    for (int f = 0; f < DIM; f += 4) {
        float4 ev = *(const float4*)(ext_gp + f);
        float q0[4], q1[4];
        #pragma unroll
        for (int j = 0; j < 4; ++j) {
            q0[j] = ((const float*)&ev)[j] * w1[(f + j) * DIM + d0];
            q1[j] = ((const float*)&ev)[j] * w1[(f + j) * DIM + d1];
        }
        #pragma unroll
        for (int k = 0; k < KNB; ++k) {
            float4 nv = *(const float4*)(nbr_s + k * DIM + f);
            acc0[k] += nv.x * q0[0] + nv.y * q0[1] + nv.z * q0[2] + nv.w * q0[3];
            acc1[k] += nv.x * q1[0] + nv.y * q1[1] + nv.z * q1[2] + nv.w * q1[3];
        }
    }
    const float* nwp = nw + (size_t)bn * KNB;
    const float w1t0 = w1[DIM * DIM + d0], w1t1 = w1[DIM * DIM + d1];
    const float w2a = w2[d0], w2b = w2[d1];
    float part[KNB];
    #pragma unroll
    for (int k = 0; k < KNB; ++k) {
        float a0 = acc0[k] + nwp[k] * w1t0, a1 = acc1[k] + nwp[k] * w1t1;
        a0 = a0 > 0.f ? a0 : 0.2f * a0; a1 = a1 > 0.f ? a1 : 0.2f * a1;
        part[k] = a0 * w2a + a1 * w2b;
    }
    #pragma unroll
    for (int k = 0; k < KNB; ++k) {
        float v = part[k];
        #pragma unroll
        for (int off = 32; off > 0; off >>= 1) v += __shfl_xor(v, off, 64);
        part[k] = v;
    }
    float mx = part[0];
    #pragma unroll
    for (int k = 1; k < KNB; ++k) mx = fmaxf(mx, part[k]);
    float s = 0.f;
    #pragma unroll
    for (int k = 0; k < KNB; ++k) { part[k] = __expf(part[k] - mx); s += part[k]; }
    const float inv = 1.f / s;
    float a0 = 0.f, a1 = 0.f;
    #pragma unroll
    for (int k = 0; k < KNB; ++k) {
        const float aw = part[k] * inv;
        a0 += aw * nbr_s[k * DIM + d0]; a1 += aw * nbr_s[k * DIM + d1];
    }
    agg[(size_t)bn * DIM + d0] = a0; agg[(size_t)bn * DIM + d1] = a1;
}

__global__ __launch_bounds__(256) void out_gemm_fb(
    const float* __restrict__ selfv, const float* __restrict__ agg,
    const float* __restrict__ w3, float* __restrict__ out)
{
    __shared__ float in_lds[64][256];
    const int row0 = blockIdx.x * 64, tid = threadIdx.x;
    for (int idx = tid; idx < 64 * 64; idx += 256) {
        const int r = idx >> 6, c4 = idx & 63;
        float4 v;
        if (c4 < 32) v = ((const float4*)(selfv + (size_t)(row0 + r) * DIM))[c4];
        else         v = ((const float4*)(agg + (size_t)(row0 + r) * DIM))[c4 - 32];
        ((float4*)in_lds[r])[c4] = v;
    }
    __syncthreads();
    const int d0 = tid & 63, rbase = (tid >> 6) * 16;
    float acc0[16], acc1[16];
    #pragma unroll
    for (int r = 0; r < 16; ++r) { acc0[r] = 0.f; acc1[r] = 0.f; }
    for (int f = 0; f < 256; f += 4) {
        float w3a[4], w3b[4];
        #pragma unroll
        for (int j = 0; j < 4; ++j) {
            w3a[j] = w3[(f + j) * DIM + d0]; w3b[j] = w3[(f + j) * DIM + d0 + 64];
        }
        #pragma unroll
        for (int r = 0; r < 16; ++r) {
            float4 iv = *(const float4*)(&in_lds[rbase + r][f]);
            acc0[r] += iv.x * w3a[0] + iv.y * w3a[1] + iv.z * w3a[2] + iv.w * w3a[3];
            acc1[r] += iv.x * w3b[0] + iv.y * w3b[1] + iv.z * w3b[2] + iv.w * w3b[3];
        }
    }
    #pragma unroll
    for (int r = 0; r < 16; ++r) {
        const size_t row = (size_t)(row0 + rbase + r);
        out[row * DIM + d0] = fmaxf(acc0[r], 0.f);
        out[row * DIM + d0 + 64] = fmaxf(acc1[r], 0.f);
    }
}

// ---------------------------------------------------------------------------
extern "C" void kernel_launch(void* const* d_in, const int* in_sizes, int n_in,
                              void* d_out, int out_size, void* d_ws, size_t ws_size,
                              hipStream_t stream) {
    const float* selfv    = (const float*)d_in[0];
    const float* neighbor = (const float*)d_in[1];
    const float* nw       = (const float*)d_in[4];
    const float* extra    = (const float*)d_in[5];
    const float* w1       = (const float*)d_in[6];
    const float* w2       = (const float*)d_in[7];
    const float* w3       = (const float*)d_in[8];
    float* out = (float*)d_out;

    // ws layout: [0,32K) w1f bf16 | [32K,96K) w3f bf16
    if (ws_size >= (size_t)96 * 1024) {
        unsigned short* w1f = (unsigned short*)d_ws;
        unsigned short* w3f = (unsigned short*)((char*)d_ws + 32 * 1024);
        prep_kernel<<<128, 256, 0, stream>>>(w1, w3, w1f, w3f);
        fused_kernel<<<BN / T1, 256, 0, stream>>>(neighbor, nw, extra, selfv,
                                                  w1, w2, w1f, w3f, out);
    } else {
        attn_agg_fb<<<BN / 2, 128, 0, stream>>>(neighbor, nw, extra, w1, w2, out);
        out_gemm_fb<<<BN / 64, 256, 0, stream>>>(selfv, out, w3, out);
    }
}

// Round 4
// 329.324 us; speedup vs baseline: 1.0633x; 1.0633x over previous
//
#include <hip/hip_runtime.h>
#include <hip/hip_bf16.h>

#define BN    32768   // B*N
#define KNB   12
#define DIM   128

typedef __attribute__((ext_vector_type(8))) short bf16x8;
typedef __attribute__((ext_vector_type(4))) float f32x4;

__device__ inline unsigned short f2b(float x) {
    union { float f; unsigned u; } v; v.f = x;
    unsigned r = v.u + 0x7fffu + ((v.u >> 16) & 1u);   // RNE
    return (unsigned short)(r >> 16);
}
__device__ inline unsigned pack2(float a, float b) {   // v_cvt_pk_bf16_f32 on gfx950
    __hip_bfloat162 h = __float22bfloat162_rn(make_float2(a, b));
    unsigned u; __builtin_memcpy(&u, &h, 4); return u;
}
__device__ inline float2 unpack2(unsigned u) {
    __hip_bfloat162 h; __builtin_memcpy(&h, &u, 4);
    return __bfloat1622float2(h);
}

// ---------------------------------------------------------------------------
// Prep: w1 (128x128 part) and w3 (256x128) -> bf16 MFMA B-fragment order.
// frag fi, lane, j -> B[k = ks*32 + (lane>>4)*8 + j][n = nt*16 + (lane&15)]
// w1f: fi = nt*4 + ks;  w3f: fi = nt*8 + ks
// ---------------------------------------------------------------------------
__global__ void prep_kernel(const float* __restrict__ w1, const float* __restrict__ w3,
                            unsigned short* __restrict__ w1f, unsigned short* __restrict__ w3f) {
    int idx = blockIdx.x * 256 + threadIdx.x;
    if (idx < 16384) {
        int j = idx & 7, lane = (idx >> 3) & 63, fi = idx >> 9;
        int nt = fi >> 2, ks = fi & 3;
        int k = ks * 32 + (lane >> 4) * 8 + j;
        int n = nt * 16 + (lane & 15);
        w1f[idx] = f2b(w1[k * DIM + n]);
    }
    if (idx < 32768) {
        int j = idx & 7, lane = (idx >> 3) & 63, fi = idx >> 9;
        int nt = fi >> 3, ks = fi & 7;
        int k = ks * 32 + (lane >> 4) * 8 + j;
        int n = nt * 16 + (lane & 15);
        w3f[idx] = f2b(w3[k * DIM + n]);
    }
}

// ---------------------------------------------------------------------------
// Fused kernel, block = 8 nodes (M1 = 96 (node,k) rows):
//  1) stage feat = extra*nbr -> bf16 LDS (ONLY feat; nbr recovered by /extra)
//  2) GEMM1 N-split: wave w computes n-tiles {2w,2w+1} for all 6 m-tiles
//     (48 MFMAs/wave, balanced); epilogue + nw*w1[128], leaky, dot w2 ->
//     per-wave partial logits -> logits_p[4][96]
//  3) softmax over K=12 (8 threads) || stage self rows into A2
//  4) agg[node][d] = (sum_k wts*feat)/extra[d] -> A2 cols 128..255
//  5) GEMM2: out[8,128] = relu(A2[8,256] @ w3)
// ---------------------------------------------------------------------------
#define T1   8
#define M1   96
#define LDA1 136    // shorts; 16B-multiple (b128-aligned), +8 pad
#define LDA2 264    // shorts; 16B-multiple, +8 pad

__global__ __launch_bounds__(256) void fused_kernel(
    const float* __restrict__ nbr_g,   // [BN,12,128]
    const float* __restrict__ nw_g,    // [BN,12]
    const float* __restrict__ ext_g,   // [BN,128]
    const float* __restrict__ selfv,   // [BN,128]
    const float* __restrict__ w1,      // [129,128] (row 128 used in epilogue)
    const float* __restrict__ w2,      // [128]
    const unsigned short* __restrict__ w1f,
    const unsigned short* __restrict__ w3f,
    float* __restrict__ out)           // [BN,128]
{
    __shared__ unsigned short featb[M1 * LDA1];          // 26112 B
    __shared__ unsigned short A2[16 * LDA2];             // 8448 B
    __shared__ float logits_p[4][M1];                    // 1536 B
    __shared__ float wts[M1];                            // 384 B

    const int tid  = threadIdx.x;
    const int lane = tid & 63;
    const int wv   = tid >> 6;
    const int bn0  = blockIdx.x * T1;

    const int node = tid >> 5;          // 0..7
    const int c4   = tid & 31;          // float4 column

    // ---- 1) stage feat: thread owns (node,c4), loops k; extra loaded once ----
    {
        const float4* nsrc = (const float4*)(nbr_g + (size_t)bn0 * KNB * DIM);
        const float4  ev   = *(const float4*)(ext_g + (size_t)(bn0 + node) * DIM + c4 * 4);
        #pragma unroll
        for (int k = 0; k < KNB; ++k) {
            float4 nv = nsrc[node * (KNB * 32) + k * 32 + c4];
            uint2 pf;
            pf.x = pack2(nv.x * ev.x, nv.y * ev.y);
            pf.y = pack2(nv.z * ev.z, nv.w * ev.w);
            *(uint2*)&featb[(node * KNB + k) * LDA1 + c4 * 4] = pf;
        }
    }
    __syncthreads();

    const int m    = lane & 15;
    const int quad = lane >> 4;
    const int nt0  = wv * 2;
    const int nt1  = wv * 2 + 1;

    // ---- 2) GEMM1 (N-split, balanced) ----
    {
        const bf16x8* w1fv = (const bf16x8*)w1f;
        bf16x8 Bf[8];                                    // 2 n-tiles x 4 ks
        #pragma unroll
        for (int ks = 0; ks < 4; ++ks) {
            Bf[ks]     = w1fv[(nt0 * 4 + ks) * 64 + lane];
            Bf[4 + ks] = w1fv[(nt1 * 4 + ks) * 64 + lane];
        }
        const float w2v0 = w2[nt0 * 16 + m], w2v1 = w2[nt1 * 16 + m];
        const float w1l0 = w1[DIM * DIM + nt0 * 16 + m];
        const float w1l1 = w1[DIM * DIM + nt1 * 16 + m];

        #pragma unroll
        for (int mt = 0; mt < 6; ++mt) {
            const int rowbase = mt * 16 + quad * 4;
            bf16x8 af[4];
            #pragma unroll
            for (int ks = 0; ks < 4; ++ks)
                af[ks] = *(const bf16x8*)&featb[(mt * 16 + m) * LDA1 + ks * 32 + quad * 8];

            f32x4 acc0 = {0.f, 0.f, 0.f, 0.f}, acc1 = {0.f, 0.f, 0.f, 0.f};
            #pragma unroll
            for (int ks = 0; ks < 4; ++ks) {
                acc0 = __builtin_amdgcn_mfma_f32_16x16x32_bf16(af[ks], Bf[ks],     acc0, 0, 0, 0);
                acc1 = __builtin_amdgcn_mfma_f32_16x16x32_bf16(af[ks], Bf[4 + ks], acc1, 0, 0, 0);
            }
            float lp[4];
            #pragma unroll
            for (int r = 0; r < 4; ++r) {
                const float nwr = nw_g[(size_t)bn0 * KNB + rowbase + r];
                float v0 = acc0[r] + nwr * w1l0;
                float v1 = acc1[r] + nwr * w1l1;
                v0 = v0 > 0.f ? v0 : 0.2f * v0;
                v1 = v1 > 0.f ? v1 : 0.2f * v1;
                lp[r] = v0 * w2v0 + v1 * w2v1;
            }
            #pragma unroll
            for (int r = 0; r < 4; ++r) {
                float v = lp[r];
                v += __shfl_xor(v, 1, 64); v += __shfl_xor(v, 2, 64);
                v += __shfl_xor(v, 4, 64); v += __shfl_xor(v, 8, 64);
                if (m == 0) logits_p[wv][rowbase + r] = v;
            }
        }
    }
    __syncthreads();

    // ---- 3) softmax (8 threads)  ||  stage self rows into A2 cols 0..127 ----
    {
        float4 sv = *(const float4*)(selfv + (size_t)(bn0 + node) * DIM + c4 * 4);
        uint2 p; p.x = pack2(sv.x, sv.y); p.y = pack2(sv.z, sv.w);
        *(uint2*)&A2[node * LDA2 + c4 * 4] = p;
    }
    if (tid < T1) {
        float l[KNB];
        #pragma unroll
        for (int k = 0; k < KNB; ++k)
            l[k] = logits_p[0][tid * KNB + k] + logits_p[1][tid * KNB + k]
                 + logits_p[2][tid * KNB + k] + logits_p[3][tid * KNB + k];
        float mx = l[0];
        #pragma unroll
        for (int k = 1; k < KNB; ++k) mx = fmaxf(mx, l[k]);
        float s = 0.f;
        #pragma unroll
        for (int k = 0; k < KNB; ++k) { l[k] = __expf(l[k] - mx); s += l[k]; }
        const float inv = 1.f / s;
        #pragma unroll
        for (int k = 0; k < KNB; ++k) wts[tid * KNB + k] = l[k] * inv;
    }
    __syncthreads();

    // ---- 4) agg = (sum_k wts*feat)/extra -> A2 cols 128..255 ----
    {
        const int dd = c4 * 4;
        float s0 = 0.f, s1 = 0.f, s2 = 0.f, s3 = 0.f;
        #pragma unroll
        for (int k = 0; k < KNB; ++k) {
            const float w = wts[node * KNB + k];
            uint2 pf = *(const uint2*)&featb[(node * KNB + k) * LDA1 + dd];
            float2 lo = unpack2(pf.x), hi = unpack2(pf.y);
            s0 += w * lo.x; s1 += w * lo.y; s2 += w * hi.x; s3 += w * hi.y;
        }
        const float4 ev = *(const float4*)(ext_g + (size_t)(bn0 + node) * DIM + dd);
        const float a0 = fabsf(ev.x) > 1e-30f ? s0 / ev.x : 0.f;
        const float a1 = fabsf(ev.y) > 1e-30f ? s1 / ev.y : 0.f;
        const float a2 = fabsf(ev.z) > 1e-30f ? s2 / ev.z : 0.f;
        const float a3 = fabsf(ev.w) > 1e-30f ? s3 / ev.w : 0.f;
        uint2 po; po.x = pack2(a0, a1); po.y = pack2(a2, a3);
        *(uint2*)&A2[node * LDA2 + 128 + dd] = po;
    }
    __syncthreads();

    // ---- 5) GEMM2: out[8,128] = relu(A2 @ w3); wave wv -> n-tiles 2wv,2wv+1 ----
    {
        const bf16x8* w3fv = (const bf16x8*)w3f;
        bf16x8 af2[8];
        #pragma unroll
        for (int ks = 0; ks < 8; ++ks)
            af2[ks] = *(const bf16x8*)&A2[m * LDA2 + ks * 32 + quad * 8];

        #pragma unroll
        for (int t = 0; t < 2; ++t) {
            const int nt = wv * 2 + t;
            f32x4 acc = {0.f, 0.f, 0.f, 0.f};
            #pragma unroll
            for (int ks = 0; ks < 8; ++ks)
                acc = __builtin_amdgcn_mfma_f32_16x16x32_bf16(af2[ks], w3fv[(nt * 8 + ks) * 64 + lane], acc, 0, 0, 0);
            #pragma unroll
            for (int r = 0; r < 4; ++r) {
                const int rl = quad * 4 + r;
                if (rl < T1)
                    out[(size_t)(bn0 + rl) * DIM + nt * 16 + m] = fmaxf(acc[r], 0.f);
            }
        }
    }
}

// ===========================================================================
// Fallback fp32 path if ws can't hold the 96 KB weight fragments.
// ===========================================================================
__global__ __launch_bounds__(128) void attn_agg_fb(
    const float* __restrict__ neighbor, const float* __restrict__ nw,
    const float* __restrict__ extra, const float* __restrict__ w1,
    const float* __restrict__ w2, float* __restrict__ agg)
{
    __shared__ float nbr_lds[2][KNB * DIM];
    const int wave = threadIdx.x >> 6, lane = threadIdx.x & 63;
    const int bn = blockIdx.x * 2 + wave;
    const float* nbr_gp = neighbor + (size_t)bn * (KNB * DIM);
    const float* ext_gp = extra + (size_t)bn * DIM;
    {
        const float4* s = (const float4*)nbr_gp;
        float4* d4 = (float4*)nbr_lds[wave];
        #pragma unroll
        for (int j = 0; j < 6; ++j) d4[lane + j * 64] = s[lane + j * 64];
    }
    __syncthreads();
    const int d0 = lane, d1 = lane + 64;
    float acc0[KNB], acc1[KNB];
    #pragma unroll
    for (int k = 0; k < KNB; ++k) { acc0[k] = 0.f; acc1[k] = 0.f; }
    const float* nbr_s = nbr_lds[wave];
    for (int f = 0; f < DIM; f += 4) {
        float4 ev = *(const float4*)(ext_gp + f);
        float q0[4], q1[4];
        #pragma unroll
        for (int j = 0; j < 4; ++j) {
            q0[j] = ((const float*)&ev)[j] * w1[(f + j) * DIM + d0];
            q1[j] = ((const float*)&ev)[j] * w1[(f + j) * DIM + d1];
        }
        #pragma unroll
        for (int k = 0; k < KNB; ++k) {
            float4 nv = *(const float4*)(nbr_s + k * DIM + f);
            acc0[k] += nv.x * q0[0] + nv.y * q0[1] + nv.z * q0[2] + nv.w * q0[3];
            acc1[k] += nv.x * q1[0] + nv.y * q1[1] + nv.z * q1[2] + nv.w * q1[3];
        }
    }
    const float* nwp = nw + (size_t)bn * KNB;
    const float w1t0 = w1[DIM * DIM + d0], w1t1 = w1[DIM * DIM + d1];
    const float w2a = w2[d0], w2b = w2[d1];
    float part[KNB];
    #pragma unroll
    for (int k = 0; k < KNB; ++k) {
        float a0 = acc0[k] + nwp[k] * w1t0, a1 = acc1[k] + nwp[k] * w1t1;
        a0 = a0 > 0.f ? a0 : 0.2f * a0; a1 = a1 > 0.f ? a1 : 0.2f * a1;
        part[k] = a0 * w2a + a1 * w2b;
    }
    #pragma unroll
    for (int k = 0; k < KNB; ++k) {
        float v = part[k];
        #pragma unroll
        for (int off = 32; off > 0; off >>= 1) v += __shfl_xor(v, off, 64);
        part[k] = v;
    }
    float mx = part[0];
    #pragma unroll
    for (int k = 1; k < KNB; ++k) mx = fmaxf(mx, part[k]);
    float s = 0.f;
    #pragma unroll
    for (int k = 0; k < KNB; ++k) { part[k] = __expf(part[k] - mx); s += part[k]; }
    const float inv = 1.f / s;
    float a0 = 0.f, a1 = 0.f;
    #pragma unroll
    for (int k = 0; k < KNB; ++k) {
        const float aw = part[k] * inv;
        a0 += aw * nbr_s[k * DIM + d0]; a1 += aw * nbr_s[k * DIM + d1];
    }
    agg[(size_t)bn * DIM + d0] = a0; agg[(size_t)bn * DIM + d1] = a1;
}

__global__ __launch_bounds__(256) void out_gemm_fb(
    const float* __restrict__ selfv, const float* __restrict__ agg,
    const float* __restrict__ w3, float* __restrict__ out)
{
    __shared__ float in_lds[64][256];
    const int row0 = blockIdx.x * 64, tid = threadIdx.x;
    for (int idx = tid; idx < 64 * 64; idx += 256) {
        const int r = idx >> 6, c4 = idx & 63;
        float4 v;
        if (c4 < 32) v = ((const float4*)(selfv + (size_t)(row0 + r) * DIM))[c4];
        else         v = ((const float4*)(agg + (size_t)(row0 + r) * DIM))[c4 - 32];
        ((float4*)in_lds[r])[c4] = v;
    }
    __syncthreads();
    const int d0 = tid & 63, rbase = (tid >> 6) * 16;
    float acc0[16], acc1[16];
    #pragma unroll
    for (int r = 0; r < 16; ++r) { acc0[r] = 0.f; acc1[r] = 0.f; }
    for (int f = 0; f < 256; f += 4) {
        float w3a[4], w3b[4];
        #pragma unroll
        for (int j = 0; j < 4; ++j) {
            w3a[j] = w3[(f + j) * DIM + d0]; w3b[j] = w3[(f + j) * DIM + d0 + 64];
        }
        #pragma unroll
        for (int r = 0; r < 16; ++r) {
            float4 iv = *(const float4*)(&in_lds[rbase + r][f]);
            acc0[r] += iv.x * w3a[0] + iv.y * w3a[1] + iv.z * w3a[2] + iv.w * w3a[3];
            acc1[r] += iv.x * w3b[0] + iv.y * w3b[1] + iv.z * w3b[2] + iv.w * w3b[3];
        }
    }
    #pragma unroll
    for (int r = 0; r < 16; ++r) {
        const size_t row = (size_t)(row0 + rbase + r);
        out[row * DIM + d0] = fmaxf(acc0[r], 0.f);
        out[row * DIM + d0 + 64] = fmaxf(acc1[r], 0.f);
    }
}

// ---------------------------------------------------------------------------
extern "C" void kernel_launch(void* const* d_in, const int* in_sizes, int n_in,
                              void* d_out, int out_size, void* d_ws, size_t ws_size,
                              hipStream_t stream) {
    const float* selfv    = (const float*)d_in[0];
    const float* neighbor = (const float*)d_in[1];
    const float* nw       = (const float*)d_in[4];
    const float* extra    = (const float*)d_in[5];
    const float* w1       = (const float*)d_in[6];
    const float* w2       = (const float*)d_in[7];
    const float* w3       = (const float*)d_in[8];
    float* out = (float*)d_out;

    // ws layout: [0,32K) w1f bf16 | [32K,96K) w3f bf16
    if (ws_size >= (size_t)96 * 1024) {
        unsigned short* w1f = (unsigned short*)d_ws;
        unsigned short* w3f = (unsigned short*)((char*)d_ws + 32 * 1024);
        prep_kernel<<<128, 256, 0, stream>>>(w1, w3, w1f, w3f);
        fused_kernel<<<BN / T1, 256, 0, stream>>>(neighbor, nw, extra, selfv,
                                                  w1, w2, w1f, w3f, out);
    } else {
        attn_agg_fb<<<BN / 2, 128, 0, stream>>>(neighbor, nw, extra, w1, w2, out);
        out_gemm_fb<<<BN / 64, 256, 0, stream>>>(selfv, out, w3, out);
    }
}